// Round 1
// baseline (5373.587 us; speedup 1.0000x reference)
//
#include <hip/hip_runtime.h>
#include <hip/hip_bf16.h>

// GCN: 3x GCNConv (512->128->64->32) + global max pool + FC(32->10) + log_softmax
// N=100000 nodes, E=1600000 edges, 64 graphs.
//
// Math factoring: norm = dinv[src]*dinv[dst].
//   agg[i] = dinv[i] * ( hs[i] + sum_{e: dst=i} hs[src_e] ),  hs = dinv .* (x@W)
//   out    = relu(agg + b)

#define DEVFN __device__ __forceinline__

DEVFN void atomAddF(float* p, float v) {
#if defined(__gfx90a__) || defined(__gfx940__) || defined(__gfx941__) || defined(__gfx942__) || defined(__gfx950__)
    unsafeAtomicAdd(p, v);   // native global_atomic_add_f32
#else
    atomicAdd(p, v);
#endif
}

// ---------------- degree / dinv ----------------
__global__ void deg_init(float* __restrict__ deg, float* __restrict__ pooled, int N) {
    int i = blockIdx.x * 256 + threadIdx.x;
    if (i < N) deg[i] = 1.0f;           // self loop
    if (i < 64 * 32) pooled[i] = 0.0f;  // pooled init (post-relu values >= 0)
}

__global__ void deg_count(const int* __restrict__ dst, float* __restrict__ deg, int E) {
    int e = blockIdx.x * 256 + threadIdx.x;
    if (e < E) atomAddF(&deg[dst[e]], 1.0f);
}

__global__ void dinv_kernel(float* __restrict__ deg, int N) {
    int i = blockIdx.x * 256 + threadIdx.x;
    if (i < N) deg[i] = rsqrtf(deg[i]);
}

// ---------------- GEMM: C[M x NOUT] = A[M x K] @ B[K x NOUT] ----------------
// 256 threads, 64 rows/block, 4-col x RPT-row register microtile.
template <int NOUT>
__global__ void gemm_kernel(const float* __restrict__ A, const float* __restrict__ B,
                            float* __restrict__ C, int M, int K) {
    constexpr int BK = 32;
    constexpr int TM = 64;
    constexpr int NC4 = NOUT / 4;       // 32 / 16 / 8 col-groups
    constexpr int TROWS = 256 / NC4;    // 8 / 16 / 32
    constexpr int RPT = TM / TROWS;     // 8 / 4 / 2 rows per thread

    __shared__ float As[TM][BK + 1];
    __shared__ float Bs[BK][NOUT];

    const int t = threadIdx.x;
    const int tc = t % NC4;
    const int tr = t / NC4;
    const int row0 = blockIdx.x * TM;

    float4 acc[RPT];
#pragma unroll
    for (int r = 0; r < RPT; ++r) acc[r] = make_float4(0.f, 0.f, 0.f, 0.f);

    for (int k0 = 0; k0 < K; k0 += BK) {
#pragma unroll
        for (int j = 0; j < TM * BK / 256; ++j) {
            int idx = t + j * 256;
            int r = idx / BK, c = idx % BK;
            int gr = row0 + r;
            As[r][c] = (gr < M) ? A[(size_t)gr * K + k0 + c] : 0.0f;
        }
#pragma unroll
        for (int j = 0; j < BK * NOUT / 256; ++j) {
            int idx = t + j * 256;
            int r = idx / NOUT, c = idx % NOUT;
            Bs[r][c] = B[(size_t)(k0 + r) * NOUT + c];
        }
        __syncthreads();

#pragma unroll
        for (int k = 0; k < BK; ++k) {
            float4 b = *(const float4*)&Bs[k][tc * 4];
#pragma unroll
            for (int r = 0; r < RPT; ++r) {
                float a = As[tr + r * TROWS][k];
                acc[r].x += a * b.x;
                acc[r].y += a * b.y;
                acc[r].z += a * b.z;
                acc[r].w += a * b.w;
            }
        }
        __syncthreads();
    }

#pragma unroll
    for (int r = 0; r < RPT; ++r) {
        int gr = row0 + tr + r * TROWS;
        if (gr < M) *(float4*)&C[(size_t)gr * NOUT + tc * 4] = acc[r];
    }
}

// ---------------- hs = dinv .* h (in place); agg = hs (self-loop init) ----------------
template <int F>
__global__ void scale_selfloop(const float* __restrict__ dinv, float* __restrict__ h,
                               float* __restrict__ agg, int N) {
    constexpr int F4 = F / 4;
    long idx = (long)blockIdx.x * 256 + threadIdx.x;
    if (idx >= (long)N * F4) return;
    int i = (int)(idx / F4);
    int f4 = (int)(idx % F4) * 4;
    float di = dinv[i];
    float4 v = *(float4*)&h[(size_t)i * F + f4];
    v.x *= di; v.y *= di; v.z *= di; v.w *= di;
    *(float4*)&h[(size_t)i * F + f4] = v;
    *(float4*)&agg[(size_t)i * F + f4] = v;
}

// ---------------- agg[dst] += hs[src] over all edges ----------------
template <int F>
__global__ void edge_scatter(const int* __restrict__ src, const int* __restrict__ dst,
                             const float* __restrict__ h, float* __restrict__ agg, int E) {
    constexpr int F4 = F / 4;
    constexpr int EPB = 256 / F4;  // edges per block
    int t = threadIdx.x;
    int le = t / F4;
    int f4 = (t % F4) * 4;
    long e = (long)blockIdx.x * EPB + le;
    if (e >= E) return;
    int s = src[e], d = dst[e];
    float4 v = *(const float4*)&h[(size_t)s * F + f4];
    float* out = &agg[(size_t)d * F + f4];
    atomAddF(out + 0, v.x);
    atomAddF(out + 1, v.y);
    atomAddF(out + 2, v.z);
    atomAddF(out + 3, v.w);
}

// ---------------- out = relu(dinv .* agg + b) ----------------
template <int F>
__global__ void bias_relu(const float* __restrict__ dinv, const float* __restrict__ agg,
                          const float* __restrict__ b, float* __restrict__ out, int N) {
    constexpr int F4 = F / 4;
    long idx = (long)blockIdx.x * 256 + threadIdx.x;
    if (idx >= (long)N * F4) return;
    int i = (int)(idx / F4);
    int f4 = (int)(idx % F4) * 4;
    float di = dinv[i];
    float4 v = *(const float4*)&agg[(size_t)i * F + f4];
    float4 bb = *(const float4*)&b[f4];
    float4 o;
    o.x = fmaxf(di * v.x + bb.x, 0.f);
    o.y = fmaxf(di * v.y + bb.y, 0.f);
    o.z = fmaxf(di * v.z + bb.z, 0.f);
    o.w = fmaxf(di * v.w + bb.w, 0.f);
    *(float4*)&out[(size_t)i * F + f4] = o;
}

// ---------------- segment max pool (batch sorted, values >= 0) ----------------
__global__ void pool_max(const float* __restrict__ h, const int* __restrict__ batch,
                         float* __restrict__ pooled, int N) {
    // thread handles 32 consecutive nodes for one feature
    int t = blockIdx.x * 256 + threadIdx.x;
    int f = t % 32;
    int i0 = (t / 32) * 32;
    if (i0 >= N) return;
    int gcur = -1;
    float vmax = 0.f;
    for (int j = 0; j < 32; ++j) {
        int i = i0 + j;
        if (i >= N) break;
        int g = batch[i];
        if (g != gcur) {
            if (gcur >= 0) atomicMax((int*)&pooled[gcur * 32 + f], __float_as_int(vmax));
            gcur = g;
            vmax = 0.f;
        }
        vmax = fmaxf(vmax, h[(size_t)i * 32 + f]);
    }
    if (gcur >= 0) atomicMax((int*)&pooled[gcur * 32 + f], __float_as_int(vmax));
}

// ---------------- head: logits = pooled @ Wfc + bfc ; log_softmax ----------------
__global__ void head_kernel(const float* __restrict__ pooled, const float* __restrict__ Wfc,
                            const float* __restrict__ bfc, float* __restrict__ out) {
    int g = threadIdx.x;  // 64 graphs
    float p[32];
#pragma unroll
    for (int f = 0; f < 32; ++f) p[f] = pooled[g * 32 + f];
    float logits[10];
#pragma unroll
    for (int c = 0; c < 10; ++c) {
        float acc = bfc[c];
#pragma unroll
        for (int f = 0; f < 32; ++f) acc += p[f] * Wfc[f * 10 + c];
        logits[c] = acc;
    }
    float m = logits[0];
#pragma unroll
    for (int c = 1; c < 10; ++c) m = fmaxf(m, logits[c]);
    float s = 0.f;
#pragma unroll
    for (int c = 0; c < 10; ++c) s += expf(logits[c] - m);
    float lse = m + logf(s);
#pragma unroll
    for (int c = 0; c < 10; ++c) out[g * 10 + c] = logits[c] - lse;
}

extern "C" void kernel_launch(void* const* d_in, const int* in_sizes, int n_in,
                              void* d_out, int out_size, void* d_ws, size_t ws_size,
                              hipStream_t stream) {
    const float* x   = (const float*)d_in[0];
    const int*   ei  = (const int*)d_in[1];
    const int*   bat = (const int*)d_in[2];
    const float* W1  = (const float*)d_in[3];
    const float* b1  = (const float*)d_in[4];
    const float* W2  = (const float*)d_in[5];
    const float* b2  = (const float*)d_in[6];
    const float* W3  = (const float*)d_in[7];
    const float* b3  = (const float*)d_in[8];
    const float* Wfc = (const float*)d_in[9];
    const float* bfc = (const float*)d_in[10];
    float* out = (float*)d_out;

    const int N = in_sizes[2];        // 100000
    const int E = in_sizes[1] / 2;    // 1600000
    const int K0 = in_sizes[0] / N;   // 512

    const int* src = ei;
    const int* dst = ei + E;

    float* ws = (float*)d_ws;
    float* dinv = ws;                            // N
    float* B1 = ws + N;                          // N*128
    float* B2 = B1 + (size_t)N * 128;            // N*128
    float* pooled = B2 + (size_t)N * 128;        // 64*32

    const int nb = (N + 255) / 256;
    const int gb = (N + 63) / 64;

    // degree / dinv (+ pooled zero-init)
    deg_init<<<nb, 256, 0, stream>>>(dinv, pooled, N);
    deg_count<<<(E + 255) / 256, 256, 0, stream>>>(dst, dinv, E);
    dinv_kernel<<<nb, 256, 0, stream>>>(dinv, N);

    // ---- layer 1: 512 -> 128 ----
    gemm_kernel<128><<<gb, 256, 0, stream>>>(x, W1, B1, N, K0);
    scale_selfloop<128><<<(int)(((long)N * 32 + 255) / 256), 256, 0, stream>>>(dinv, B1, B2, N);
    edge_scatter<128><<<(E + 7) / 8, 256, 0, stream>>>(src, dst, B1, B2, E);
    bias_relu<128><<<(int)(((long)N * 32 + 255) / 256), 256, 0, stream>>>(dinv, B2, b1, B1, N);

    // ---- layer 2: 128 -> 64 ----
    gemm_kernel<64><<<gb, 256, 0, stream>>>(B1, W2, B2, N, 128);
    scale_selfloop<64><<<(int)(((long)N * 16 + 255) / 256), 256, 0, stream>>>(dinv, B2, B1, N);
    edge_scatter<64><<<(E + 15) / 16, 256, 0, stream>>>(src, dst, B2, B1, E);
    bias_relu<64><<<(int)(((long)N * 16 + 255) / 256), 256, 0, stream>>>(dinv, B1, b2, B2, N);

    // ---- layer 3: 64 -> 32 ----
    gemm_kernel<32><<<gb, 256, 0, stream>>>(B2, W3, B1, N, 64);
    scale_selfloop<32><<<(int)(((long)N * 8 + 255) / 256), 256, 0, stream>>>(dinv, B1, B2, N);
    edge_scatter<32><<<(E + 31) / 32, 256, 0, stream>>>(src, dst, B1, B2, E);
    bias_relu<32><<<(int)(((long)N * 8 + 255) / 256), 256, 0, stream>>>(dinv, B2, b3, B1, N);

    // ---- pool + head ----
    pool_max<<<(int)(((long)((N + 31) / 32) * 32 + 255) / 256), 256, 0, stream>>>(B1, bat, pooled, N);
    head_kernel<<<1, 64, 0, stream>>>(pooled, Wfc, bfc, out);
}

// Round 3
// 1026.226 us; speedup vs baseline: 5.2363x; 5.2363x over previous
//
#include <hip/hip_runtime.h>
#include <hip/hip_bf16.h>

// GCN: 3x GCNConv (512->128->64->32) + global max pool + FC(32->10) + log_softmax
// N=100000 nodes, E=1600000 edges, 64 graphs.
//
// Round 3: CSR gather (round 2) with FIXED gather grid sizes
// (round 2 launched ~1/8 of the required blocks for gather_relu).
//   agg[i] = dinv[i] * ( hs[i] + sum_{j in in(i)} hs[j] ),  hs = dinv .* (x@W)  (dinv fused in GEMM)
//   out    = relu(agg + b)                                   (fused in gather)

// ---------------- init: zero deg counters + pooled ----------------
__global__ void init_kernel(int* __restrict__ cnt, float* __restrict__ pooled, int N) {
    int i = blockIdx.x * 256 + threadIdx.x;
    if (i < N) cnt[i] = 0;
    if (i < 64 * 32) pooled[i] = 0.0f;  // post-relu values >= 0, so 0-init is a valid max identity
}

__global__ void deg_count(const int* __restrict__ dst, int* __restrict__ cnt, int E) {
    int e = blockIdx.x * 256 + threadIdx.x;
    if (e < E) atomicAdd(&cnt[dst[e]], 1);
}

__global__ void dinv_kernel(const int* __restrict__ cnt, float* __restrict__ dinv, int N) {
    int i = blockIdx.x * 256 + threadIdx.x;
    if (i < N) dinv[i] = rsqrtf(1.0f + (float)cnt[i]);  // +1 self loop
}

// ---------------- exclusive scan of cnt -> rowstart (3-phase) ----------------
__global__ void scan1(const int* __restrict__ cnt, int* __restrict__ rowstart,
                      int* __restrict__ bsums, int N) {
    __shared__ int s[256];
    int i = blockIdx.x * 256 + threadIdx.x;
    int v = (i < N) ? cnt[i] : 0;
    s[threadIdx.x] = v;
    __syncthreads();
    for (int off = 1; off < 256; off <<= 1) {
        int t = (threadIdx.x >= off) ? s[threadIdx.x - off] : 0;
        __syncthreads();
        s[threadIdx.x] += t;
        __syncthreads();
    }
    if (i < N) rowstart[i] = s[threadIdx.x] - v;  // exclusive
    if (threadIdx.x == 255) bsums[blockIdx.x] = s[255];
}

__global__ void scan2(int* __restrict__ bsums, int nb) {
    __shared__ int s[512];
    int t = threadIdx.x;
    int v = (t < nb) ? bsums[t] : 0;
    s[t] = v;
    __syncthreads();
    for (int off = 1; off < 512; off <<= 1) {
        int u = (t >= off) ? s[t - off] : 0;
        __syncthreads();
        s[t] += u;
        __syncthreads();
    }
    if (t < nb) bsums[t] = s[t] - v;  // exclusive
}

__global__ void scan3(int* __restrict__ rowstart, const int* __restrict__ bsums,
                      int* __restrict__ cursor, int N, int E) {
    int i = blockIdx.x * 256 + threadIdx.x;
    if (i < N) {
        int r = rowstart[i] + bsums[blockIdx.x];
        rowstart[i] = r;
        cursor[i] = r;
    }
    if (i == 0) rowstart[N] = E;
}

__global__ void fill_adj(const int* __restrict__ src, const int* __restrict__ dst,
                         int* __restrict__ cursor, int* __restrict__ adj, int E) {
    int e = blockIdx.x * 256 + threadIdx.x;
    if (e < E) {
        int pos = atomicAdd(&cursor[dst[e]], 1);
        adj[pos] = src[e];
    }
}

// ---------------- GEMM: C[M x NOUT] = dinv .* (A[M x K] @ B[K x NOUT]) ----------------
template <int NOUT>
__global__ void gemm_kernel(const float* __restrict__ A, const float* __restrict__ B,
                            const float* __restrict__ dinv, float* __restrict__ C,
                            int M, int K) {
    constexpr int BK = 32;
    constexpr int TM = 64;
    constexpr int NC4 = NOUT / 4;
    constexpr int TROWS = 256 / NC4;
    constexpr int RPT = TM / TROWS;

    __shared__ float As[TM][BK + 1];
    __shared__ float Bs[BK][NOUT];

    const int t = threadIdx.x;
    const int tc = t % NC4;
    const int tr = t / NC4;
    const int row0 = blockIdx.x * TM;

    float4 acc[RPT];
#pragma unroll
    for (int r = 0; r < RPT; ++r) acc[r] = make_float4(0.f, 0.f, 0.f, 0.f);

    for (int k0 = 0; k0 < K; k0 += BK) {
#pragma unroll
        for (int j = 0; j < TM * BK / 256; ++j) {
            int idx = t + j * 256;
            int r = idx / BK, c = idx % BK;
            int gr = row0 + r;
            As[r][c] = (gr < M) ? A[(size_t)gr * K + k0 + c] : 0.0f;
        }
#pragma unroll
        for (int j = 0; j < BK * NOUT / 256; ++j) {
            int idx = t + j * 256;
            int r = idx / NOUT, c = idx % NOUT;
            Bs[r][c] = B[(size_t)(k0 + r) * NOUT + c];
        }
        __syncthreads();

#pragma unroll
        for (int k = 0; k < BK; ++k) {
            float4 b = *(const float4*)&Bs[k][tc * 4];
#pragma unroll
            for (int r = 0; r < RPT; ++r) {
                float a = As[tr + r * TROWS][k];
                acc[r].x += a * b.x;
                acc[r].y += a * b.y;
                acc[r].z += a * b.z;
                acc[r].w += a * b.w;
            }
        }
        __syncthreads();
    }

#pragma unroll
    for (int r = 0; r < RPT; ++r) {
        int gr = row0 + tr + r * TROWS;
        if (gr < M) {
            float di = dinv[gr];
            float4 o = acc[r];
            o.x *= di; o.y *= di; o.z *= di; o.w *= di;
            *(float4*)&C[(size_t)gr * NOUT + tc * 4] = o;
        }
    }
}

// ---------------- gather: out = relu(dinv .* (hs[i] + sum_{in-edges} hs[src]) + b) ----------------
template <int F>
__global__ void gather_relu(const int* __restrict__ rowstart, const int* __restrict__ adj,
                            const float* __restrict__ dinv, const float* __restrict__ hs,
                            const float* __restrict__ bias, float* __restrict__ out, int N) {
    constexpr int F4 = F / 4;          // lanes per node
    constexpr int NPB = 256 / F4;      // nodes per block
    const int node = blockIdx.x * NPB + threadIdx.x / F4;
    if (node >= N) return;
    const int lane = threadIdx.x % F4;
    const size_t fo = (size_t)lane * 4;

    float4 acc = *(const float4*)&hs[(size_t)node * F + fo];  // self loop
    int j = rowstart[node];
    const int end = rowstart[node + 1];

    for (; j + 4 <= end; j += 4) {
        int s0 = adj[j], s1 = adj[j + 1], s2 = adj[j + 2], s3 = adj[j + 3];
        float4 v0 = *(const float4*)&hs[(size_t)s0 * F + fo];
        float4 v1 = *(const float4*)&hs[(size_t)s1 * F + fo];
        float4 v2 = *(const float4*)&hs[(size_t)s2 * F + fo];
        float4 v3 = *(const float4*)&hs[(size_t)s3 * F + fo];
        acc.x += (v0.x + v1.x) + (v2.x + v3.x);
        acc.y += (v0.y + v1.y) + (v2.y + v3.y);
        acc.z += (v0.z + v1.z) + (v2.z + v3.z);
        acc.w += (v0.w + v1.w) + (v2.w + v3.w);
    }
    for (; j < end; ++j) {
        int s = adj[j];
        float4 v = *(const float4*)&hs[(size_t)s * F + fo];
        acc.x += v.x; acc.y += v.y; acc.z += v.z; acc.w += v.w;
    }

    const float di = dinv[node];
    float4 bb = *(const float4*)&bias[fo];
    float4 o;
    o.x = fmaxf(di * acc.x + bb.x, 0.f);
    o.y = fmaxf(di * acc.y + bb.y, 0.f);
    o.z = fmaxf(di * acc.z + bb.z, 0.f);
    o.w = fmaxf(di * acc.w + bb.w, 0.f);
    *(float4*)&out[(size_t)node * F + fo] = o;
}

// ---------------- segment max pool (batch sorted, values >= 0) ----------------
__global__ void pool_max(const float* __restrict__ h, const int* __restrict__ batch,
                         float* __restrict__ pooled, int N) {
    int t = blockIdx.x * 256 + threadIdx.x;
    int f = t % 32;
    int i0 = (t / 32) * 32;
    if (i0 >= N) return;
    int gcur = -1;
    float vmax = 0.f;
    for (int j = 0; j < 32; ++j) {
        int i = i0 + j;
        if (i >= N) break;
        int g = batch[i];
        if (g != gcur) {
            if (gcur >= 0) atomicMax((int*)&pooled[gcur * 32 + f], __float_as_int(vmax));
            gcur = g;
            vmax = 0.f;
        }
        vmax = fmaxf(vmax, h[(size_t)i * 32 + f]);
    }
    if (gcur >= 0) atomicMax((int*)&pooled[gcur * 32 + f], __float_as_int(vmax));
}

// ---------------- head: logits = pooled @ Wfc + bfc ; log_softmax ----------------
__global__ void head_kernel(const float* __restrict__ pooled, const float* __restrict__ Wfc,
                            const float* __restrict__ bfc, float* __restrict__ out) {
    int g = threadIdx.x;  // 64 graphs
    float p[32];
#pragma unroll
    for (int f = 0; f < 32; ++f) p[f] = pooled[g * 32 + f];
    float logits[10];
#pragma unroll
    for (int c = 0; c < 10; ++c) {
        float acc = bfc[c];
#pragma unroll
        for (int f = 0; f < 32; ++f) acc += p[f] * Wfc[f * 10 + c];
        logits[c] = acc;
    }
    float m = logits[0];
#pragma unroll
    for (int c = 1; c < 10; ++c) m = fmaxf(m, logits[c]);
    float s = 0.f;
#pragma unroll
    for (int c = 0; c < 10; ++c) s += expf(logits[c] - m);
    float lse = m + logf(s);
#pragma unroll
    for (int c = 0; c < 10; ++c) out[g * 10 + c] = logits[c] - lse;
}

extern "C" void kernel_launch(void* const* d_in, const int* in_sizes, int n_in,
                              void* d_out, int out_size, void* d_ws, size_t ws_size,
                              hipStream_t stream) {
    const float* x   = (const float*)d_in[0];
    const int*   ei  = (const int*)d_in[1];
    const int*   bat = (const int*)d_in[2];
    const float* W1  = (const float*)d_in[3];
    const float* b1  = (const float*)d_in[4];
    const float* W2  = (const float*)d_in[5];
    const float* b2  = (const float*)d_in[6];
    const float* W3  = (const float*)d_in[7];
    const float* b3  = (const float*)d_in[8];
    const float* Wfc = (const float*)d_in[9];
    const float* bfc = (const float*)d_in[10];
    float* out = (float*)d_out;

    const int N = in_sizes[2];        // 100000
    const int E = in_sizes[1] / 2;    // 1600000
    const int K0 = in_sizes[0] / N;   // 512

    const int* src = ei;
    const int* dst = ei + E;

    float* ws = (float*)d_ws;
    float* dinv = ws;                              // N
    float* B1 = ws + N;                            // N*128
    float* B2 = B1 + (size_t)N * 128;              // N*128
    float* pooled = B2 + (size_t)N * 128;          // 2048
    int* iws = (int*)(pooled + 2048);
    int* rowstart = iws;                           // N+1
    int* cursor = rowstart + (N + 1);              // N
    int* bsums = cursor + N;                       // 1024
    int* adj = bsums + 1024;                       // E

    const int nb = (N + 255) / 256;                // 391
    const int eb = (E + 255) / 256;
    const int gb = (N + 63) / 64;

    // ---- CSR build + dinv ----
    init_kernel<<<nb, 256, 0, stream>>>(cursor, pooled, N);
    deg_count<<<eb, 256, 0, stream>>>(dst, cursor, E);
    dinv_kernel<<<nb, 256, 0, stream>>>(cursor, dinv, N);
    scan1<<<nb, 256, 0, stream>>>(cursor, rowstart, bsums, N);
    scan2<<<1, 512, 0, stream>>>(bsums, nb);
    scan3<<<nb, 256, 0, stream>>>(rowstart, bsums, cursor, N, E);
    fill_adj<<<eb, 256, 0, stream>>>(src, dst, cursor, adj, E);

    // gather grids: NPB = 256/(F/4) nodes per block -> ceil(N/NPB) blocks
    const int gath128 = (N + 7) / 8;     // F=128: 8 nodes/block
    const int gath64  = (N + 15) / 16;   // F=64: 16 nodes/block
    const int gath32  = (N + 31) / 32;   // F=32: 32 nodes/block

    // ---- layer 1: 512 -> 128 ----
    gemm_kernel<128><<<gb, 256, 0, stream>>>(x, W1, dinv, B1, N, K0);
    gather_relu<128><<<gath128, 256, 0, stream>>>(rowstart, adj, dinv, B1, b1, B2, N);

    // ---- layer 2: 128 -> 64 ----
    gemm_kernel<64><<<gb, 256, 0, stream>>>(B2, W2, dinv, B1, N, 128);
    gather_relu<64><<<gath64, 256, 0, stream>>>(rowstart, adj, dinv, B1, b2, B2, N);

    // ---- layer 3: 64 -> 32 ----
    gemm_kernel<32><<<gb, 256, 0, stream>>>(B2, W3, dinv, B1, N, 64);
    gather_relu<32><<<gath32, 256, 0, stream>>>(rowstart, adj, dinv, B1, b3, B2, N);

    // ---- pool + head ----
    pool_max<<<(((N + 31) / 32) * 32 + 255) / 256, 256, 0, stream>>>(B2, bat, pooled, N);
    head_kernel<<<1, 64, 0, stream>>>(pooled, Wfc, bfc, out);
}

// Round 4
// 770.566 us; speedup vs baseline: 6.9736x; 1.3318x over previous
//
#include <hip/hip_runtime.h>
#include <hip/hip_bf16.h>

// GCN: 3x GCNConv (512->128->64->32) + global max pool + FC(32->10) + log_softmax
// N=100000 nodes, E=1600000 edges, 64 graphs.
//
// Round 4: MFMA bf16 GEMMs (16x16x32), bf16 inter-layer activations.
//   hs = dinv .* (x@W)        [MFMA GEMM, dinv fused in epilogue, f32 out]
//   out = relu(dinv.*(hs[i] + sum_nbr hs) + b)   [gather, bf16 out for next GEMM]

typedef __attribute__((ext_vector_type(8))) short short8;
typedef __attribute__((ext_vector_type(4))) float f32x4;

__device__ __forceinline__ unsigned short f2bf(float f) {
    __hip_bfloat16 h = __float2bfloat16(f);
    return *(unsigned short*)&h;
}
__device__ __forceinline__ float bf2f(unsigned short u) {
    __hip_bfloat16 h = *(__hip_bfloat16*)&u;
    return __bfloat162float(h);
}

// ---------------- init: zero deg counters + pooled ----------------
__global__ void init_kernel(int* __restrict__ cnt, float* __restrict__ pooled, int N) {
    int i = blockIdx.x * 256 + threadIdx.x;
    if (i < N) cnt[i] = 0;
    if (i < 64 * 32) pooled[i] = 0.0f;  // post-relu values >= 0
}

__global__ void deg_count(const int* __restrict__ dst, int* __restrict__ cnt, int E) {
    int e = blockIdx.x * 256 + threadIdx.x;
    if (e < E) atomicAdd(&cnt[dst[e]], 1);
}

__global__ void dinv_kernel(const int* __restrict__ cnt, float* __restrict__ dinv, int N) {
    int i = blockIdx.x * 256 + threadIdx.x;
    if (i < N) dinv[i] = rsqrtf(1.0f + (float)cnt[i]);  // +1 self loop
}

// ---------------- exclusive scan of cnt -> rowstart (3-phase) ----------------
__global__ void scan1(const int* __restrict__ cnt, int* __restrict__ rowstart,
                      int* __restrict__ bsums, int N) {
    __shared__ int s[256];
    int i = blockIdx.x * 256 + threadIdx.x;
    int v = (i < N) ? cnt[i] : 0;
    s[threadIdx.x] = v;
    __syncthreads();
    for (int off = 1; off < 256; off <<= 1) {
        int t = (threadIdx.x >= off) ? s[threadIdx.x - off] : 0;
        __syncthreads();
        s[threadIdx.x] += t;
        __syncthreads();
    }
    if (i < N) rowstart[i] = s[threadIdx.x] - v;  // exclusive
    if (threadIdx.x == 255) bsums[blockIdx.x] = s[255];
}

__global__ void scan2(int* __restrict__ bsums, int nb) {
    __shared__ int s[512];
    int t = threadIdx.x;
    int v = (t < nb) ? bsums[t] : 0;
    s[t] = v;
    __syncthreads();
    for (int off = 1; off < 512; off <<= 1) {
        int u = (t >= off) ? s[t - off] : 0;
        __syncthreads();
        s[t] += u;
        __syncthreads();
    }
    if (t < nb) bsums[t] = s[t] - v;  // exclusive
}

__global__ void scan3(int* __restrict__ rowstart, const int* __restrict__ bsums,
                      int* __restrict__ cursor, int N, int E) {
    int i = blockIdx.x * 256 + threadIdx.x;
    if (i < N) {
        int r = rowstart[i] + bsums[blockIdx.x];
        rowstart[i] = r;
        cursor[i] = r;
    }
    if (i == 0) rowstart[N] = E;
}

__global__ void fill_adj(const int* __restrict__ src, const int* __restrict__ dst,
                         int* __restrict__ cursor, int* __restrict__ adj, int E) {
    int e = blockIdx.x * 256 + threadIdx.x;
    if (e < E) {
        int pos = atomicAdd(&cursor[dst[e]], 1);
        adj[pos] = src[e];
    }
}

// ---------------- W[K][N] f32 -> Wt[N][K] bf16 ----------------
__global__ void wconv(const float* __restrict__ W, unsigned short* __restrict__ Wt,
                      int K, int N) {
    int idx = blockIdx.x * 256 + threadIdx.x;
    if (idx < N * K) {
        int n = idx / K, k = idx % K;
        Wt[idx] = f2bf(W[(size_t)k * N + n]);
    }
}

// ---------------- MFMA GEMM: C[M x NOUT] = dinv .* (A[M x K] @ Wt^T) ----------------
// A is f32 (A_BF16=false) or bf16 (A_BF16=true). Wt is bf16 [NOUT][K].
// Block: 256 threads = 4 waves; tile 64 rows x NOUT cols; BK=32.
// LDS fragment order: chunk = (rowgroup|coltile)*4 + kquad; per-chunk 16 frags of
// 8 bf16 + 1 pad frag (stride 136 shorts) to spread banks.
template <int NOUT, bool A_BF16>
__global__ __launch_bounds__(256) void mfma_gemm(
        const float* __restrict__ Af, const unsigned short* __restrict__ Ab,
        const unsigned short* __restrict__ Wt, const float* __restrict__ dinv,
        float* __restrict__ C, int M, int K) {
    constexpr int NT = NOUT / 16;            // col tiles per wave: 8/4/2
    constexpr int CH = 136;                  // shorts per chunk (16*8 + 8 pad)

    __shared__ short As[16 * CH];            // 16 chunks (4 rowgroups x 4 kquads)
    __shared__ short Bs[NT * 4 * CH];        // NT*4 chunks

    const int t = threadIdx.x;
    const int w = t >> 6;                    // wave 0..3
    const int lane = t & 63;
    const int row0 = blockIdx.x * 64;

    f32x4 acc[NT];
#pragma unroll
    for (int c = 0; c < NT; ++c) acc[c] = (f32x4){0.f, 0.f, 0.f, 0.f};

    // staging coords
    const int ar = t >> 2;                   // A row 0..63
    const int aq = t & 3;                    // A k-quad
    const int arow = row0 + ar;
    const int a_lds = ((ar >> 4) * 4 + aq) * CH + (ar & 15) * 8;

    const int bn = t >> 1;                   // Wt row (col of W)
    const int bh = t & 1;                    // k-half
    const int b_lds0 = ((bn >> 4) * 4 + 2 * bh) * CH + (bn & 15) * 8;

    for (int k0 = 0; k0 < K; k0 += 32) {
        // ---- stage A (64 x 32) ----
        short8 apack;
        if (A_BF16) {
            if (arow < M) apack = *(const short8*)&Ab[(size_t)arow * K + k0 + aq * 8];
            else apack = (short8){0, 0, 0, 0, 0, 0, 0, 0};
        } else {
            float4 u0 = make_float4(0.f, 0.f, 0.f, 0.f), u1 = u0;
            if (arow < M) {
                const float* ap = Af + (size_t)arow * K + k0 + aq * 8;
                u0 = *(const float4*)ap;
                u1 = *(const float4*)(ap + 4);
            }
            apack[0] = (short)f2bf(u0.x); apack[1] = (short)f2bf(u0.y);
            apack[2] = (short)f2bf(u0.z); apack[3] = (short)f2bf(u0.w);
            apack[4] = (short)f2bf(u1.x); apack[5] = (short)f2bf(u1.y);
            apack[6] = (short)f2bf(u1.z); apack[7] = (short)f2bf(u1.w);
        }
        // ---- stage B (NOUT x 32 of Wt) ----
        short8 w0, w1;
        if (t < 2 * NOUT) {
            const unsigned short* wp = Wt + (size_t)bn * K + k0 + 16 * bh;
            w0 = *(const short8*)wp;
            w1 = *(const short8*)(wp + 8);
        }
        __syncthreads();  // previous iteration's reads done
        *(short8*)&As[a_lds] = apack;
        if (t < 2 * NOUT) {
            *(short8*)&Bs[b_lds0] = w0;
            *(short8*)&Bs[b_lds0 + CH] = w1;
        }
        __syncthreads();

        // ---- compute: each wave does rows [16w,16w+16) x all NOUT cols ----
        short8 a = *(short8*)&As[(w * 4 + (lane >> 4)) * CH + (lane & 15) * 8];
#pragma unroll
        for (int c = 0; c < NT; ++c) {
            short8 b = *(short8*)&Bs[(c * 4 + (lane >> 4)) * CH + (lane & 15) * 8];
            acc[c] = __builtin_amdgcn_mfma_f32_16x16x32_bf16(a, b, acc[c], 0, 0, 0);
        }
    }

    // ---- epilogue: C[row][col], row = row0+16w+quad*4+reg, col = 16c+(lane&15) ----
    const int q = lane >> 4, i = lane & 15;
#pragma unroll
    for (int reg = 0; reg < 4; ++reg) {
        int row = row0 + w * 16 + q * 4 + reg;
        if (row < M) {
            float di = dinv[row];
#pragma unroll
            for (int c = 0; c < NT; ++c)
                C[(size_t)row * NOUT + c * 16 + i] = di * acc[c][reg];
        }
    }
}

// ---------------- gather: out = relu(dinv .* (hs[i] + sum_in hs[src]) + b) ----------------
template <int F, bool OUT_BF16>
__global__ void gather_relu(const int* __restrict__ rowstart, const int* __restrict__ adj,
                            const float* __restrict__ dinv, const float* __restrict__ hs,
                            const float* __restrict__ bias, void* __restrict__ outv, int N) {
    constexpr int F4 = F / 4;
    constexpr int NPB = 256 / F4;
    const int node = blockIdx.x * NPB + threadIdx.x / F4;
    if (node >= N) return;
    const int lane = threadIdx.x % F4;
    const size_t fo = (size_t)lane * 4;

    float4 acc = *(const float4*)&hs[(size_t)node * F + fo];  // self loop
    int j = rowstart[node];
    const int end = rowstart[node + 1];

    for (; j + 4 <= end; j += 4) {
        int s0 = adj[j], s1 = adj[j + 1], s2 = adj[j + 2], s3 = adj[j + 3];
        float4 v0 = *(const float4*)&hs[(size_t)s0 * F + fo];
        float4 v1 = *(const float4*)&hs[(size_t)s1 * F + fo];
        float4 v2 = *(const float4*)&hs[(size_t)s2 * F + fo];
        float4 v3 = *(const float4*)&hs[(size_t)s3 * F + fo];
        acc.x += (v0.x + v1.x) + (v2.x + v3.x);
        acc.y += (v0.y + v1.y) + (v2.y + v3.y);
        acc.z += (v0.z + v1.z) + (v2.z + v3.z);
        acc.w += (v0.w + v1.w) + (v2.w + v3.w);
    }
    for (; j < end; ++j) {
        int s = adj[j];
        float4 v = *(const float4*)&hs[(size_t)s * F + fo];
        acc.x += v.x; acc.y += v.y; acc.z += v.z; acc.w += v.w;
    }

    const float di = dinv[node];
    float4 bb = *(const float4*)&bias[fo];
    float ox = fmaxf(di * acc.x + bb.x, 0.f);
    float oy = fmaxf(di * acc.y + bb.y, 0.f);
    float oz = fmaxf(di * acc.z + bb.z, 0.f);
    float ow = fmaxf(di * acc.w + bb.w, 0.f);
    if (OUT_BF16) {
        ushort4 o;
        o.x = f2bf(ox); o.y = f2bf(oy); o.z = f2bf(oz); o.w = f2bf(ow);
        *(ushort4*)&((unsigned short*)outv)[(size_t)node * F + fo] = o;
    } else {
        float4 o = make_float4(ox, oy, oz, ow);
        *(float4*)&((float*)outv)[(size_t)node * F + fo] = o;
    }
}

// ---------------- segment max pool (batch sorted, values >= 0) ----------------
__global__ void pool_max(const float* __restrict__ h, const int* __restrict__ batch,
                         float* __restrict__ pooled, int N) {
    int t = blockIdx.x * 256 + threadIdx.x;
    int f = t % 32;
    int i0 = (t / 32) * 32;
    if (i0 >= N) return;
    int gcur = -1;
    float vmax = 0.f;
    for (int j = 0; j < 32; ++j) {
        int i = i0 + j;
        if (i >= N) break;
        int g = batch[i];
        if (g != gcur) {
            if (gcur >= 0) atomicMax((int*)&pooled[gcur * 32 + f], __float_as_int(vmax));
            gcur = g;
            vmax = 0.f;
        }
        vmax = fmaxf(vmax, h[(size_t)i * 32 + f]);
    }
    if (gcur >= 0) atomicMax((int*)&pooled[gcur * 32 + f], __float_as_int(vmax));
}

// ---------------- head ----------------
__global__ void head_kernel(const float* __restrict__ pooled, const float* __restrict__ Wfc,
                            const float* __restrict__ bfc, float* __restrict__ out) {
    int g = threadIdx.x;  // 64 graphs
    float p[32];
#pragma unroll
    for (int f = 0; f < 32; ++f) p[f] = pooled[g * 32 + f];
    float logits[10];
#pragma unroll
    for (int c = 0; c < 10; ++c) {
        float acc = bfc[c];
#pragma unroll
        for (int f = 0; f < 32; ++f) acc += p[f] * Wfc[f * 10 + c];
        logits[c] = acc;
    }
    float m = logits[0];
#pragma unroll
    for (int c = 1; c < 10; ++c) m = fmaxf(m, logits[c]);
    float s = 0.f;
#pragma unroll
    for (int c = 0; c < 10; ++c) s += expf(logits[c] - m);
    float lse = m + logf(s);
#pragma unroll
    for (int c = 0; c < 10; ++c) out[g * 10 + c] = logits[c] - lse;
}

extern "C" void kernel_launch(void* const* d_in, const int* in_sizes, int n_in,
                              void* d_out, int out_size, void* d_ws, size_t ws_size,
                              hipStream_t stream) {
    const float* x   = (const float*)d_in[0];
    const int*   ei  = (const int*)d_in[1];
    const int*   bat = (const int*)d_in[2];
    const float* W1  = (const float*)d_in[3];
    const float* b1  = (const float*)d_in[4];
    const float* W2  = (const float*)d_in[5];
    const float* b2  = (const float*)d_in[6];
    const float* W3  = (const float*)d_in[7];
    const float* b3  = (const float*)d_in[8];
    const float* Wfc = (const float*)d_in[9];
    const float* bfc = (const float*)d_in[10];
    float* out = (float*)d_out;

    const int N = in_sizes[2];        // 100000
    const int E = in_sizes[1] / 2;    // 1600000
    const int K0 = in_sizes[0] / N;   // 512

    const int* src = ei;
    const int* dst = ei + E;

    float* ws = (float*)d_ws;
    float* dinv = ws;                              // N
    float* B1 = ws + N;                            // N*128 f32 (GEMM out)
    float* Bbf = B1 + (size_t)N * 128;             // N*64 words = N*128 bf16 (activations / final f32 h3)
    float* pooled = Bbf + (size_t)N * 64;          // 2048
    unsigned short* Wt1 = (unsigned short*)(pooled + 2048);  // 128*512 bf16
    unsigned short* Wt2 = Wt1 + 128 * 512;                   // 64*128
    unsigned short* Wt3 = Wt2 + 64 * 128;                    // 32*64
    int* iws = (int*)(Wt3 + 32 * 64);
    int* rowstart = iws;                           // N+1
    int* cursor = rowstart + (N + 1);              // N
    int* bsums = cursor + N;                       // 1024
    int* adj = bsums + 1024;                       // E

    unsigned short* Ab = (unsigned short*)Bbf;
    float* H3 = Bbf;                               // gather3 f32 output region

    const int nb = (N + 255) / 256;
    const int eb = (E + 255) / 256;
    const int gb = (N + 63) / 64;                  // 1563

    // ---- CSR build + dinv ----
    init_kernel<<<nb, 256, 0, stream>>>(cursor, pooled, N);
    deg_count<<<eb, 256, 0, stream>>>(dst, cursor, E);
    dinv_kernel<<<nb, 256, 0, stream>>>(cursor, dinv, N);
    scan1<<<nb, 256, 0, stream>>>(cursor, rowstart, bsums, N);
    scan2<<<1, 512, 0, stream>>>(bsums, nb);
    scan3<<<nb, 256, 0, stream>>>(rowstart, bsums, cursor, N, E);
    fill_adj<<<eb, 256, 0, stream>>>(src, dst, cursor, adj, E);

    // ---- weight transpose+convert ----
    wconv<<<(128 * 512 + 255) / 256, 256, 0, stream>>>(W1, Wt1, K0, 128);
    wconv<<<(64 * 128 + 255) / 256, 256, 0, stream>>>(W2, Wt2, 128, 64);
    wconv<<<(32 * 64 + 255) / 256, 256, 0, stream>>>(W3, Wt3, 64, 32);

    const int gath128 = (N + 7) / 8;
    const int gath64  = (N + 15) / 16;
    const int gath32  = (N + 31) / 32;

    // ---- layer 1: 512 -> 128 (A = x f32) ----
    mfma_gemm<128, false><<<gb, 256, 0, stream>>>(x, nullptr, Wt1, dinv, B1, N, K0);
    gather_relu<128, true><<<gath128, 256, 0, stream>>>(rowstart, adj, dinv, B1, b1, Ab, N);

    // ---- layer 2: 128 -> 64 (A = bf16 activations) ----
    mfma_gemm<64, true><<<gb, 256, 0, stream>>>(nullptr, Ab, Wt2, dinv, B1, N, 128);
    gather_relu<64, true><<<gath64, 256, 0, stream>>>(rowstart, adj, dinv, B1, b2, Ab, N);

    // ---- layer 3: 64 -> 32 ----
    mfma_gemm<32, true><<<gb, 256, 0, stream>>>(nullptr, Ab, Wt3, dinv, B1, N, 64);
    gather_relu<32, false><<<gath32, 256, 0, stream>>>(rowstart, adj, dinv, B1, b3, H3, N);

    // ---- pool + head ----
    pool_max<<<(((N + 31) / 32) * 32 + 255) / 256, 256, 0, stream>>>(H3, bat, pooled, N);
    head_kernel<<<1, 64, 0, stream>>>(pooled, Wfc, bfc, out);
}